// Round 15
// baseline (219.356 us; speedup 1.0000x reference)
//
#include <hip/hip_runtime.h>
#include <hip/hip_fp16.h>
#include <math.h>

// ---------------------------------------------------------------------------
// GAT 2-layer network. MFMA fp16 GEMMs (fp32 accum); fp16 gathered features;
// max-free edge softmax; CSR via binned counting-sort (packed uint32 entries).
// Quad-edge gathers in both aggr layers: 4 edges/broadcast step, quarter-wave
// cndmask select, 16B/lane (l1) / 8B/lane (l2) loads, pk_fma_f16 accum.
// N=100000, E=1600000 (+N self-loops), d_in=h1=128, h2=64.
// ---------------------------------------------------------------------------

constexpr int NPARTS = 256;   // fixed-width dst partitions
constexpr int PCAP = 8192;    // entries per partition (avg 6640, +19 sigma)
constexpr int CHUNK = 4096;   // edges per phase-A block-chunk
constexpr int DPPMAX = 400;   // max dsts per partition (391) -> dloc < 2^15
constexpr int SRCB = 17;      // src id bits (N=100000 < 2^17)

typedef _Float16 f16x8 __attribute__((ext_vector_type(8)));
typedef float f32x4 __attribute__((ext_vector_type(4)));

__device__ __forceinline__ int bcasti(int v, int j) {
  return __builtin_amdgcn_readlane(v, j);
}
__device__ __forceinline__ float bcastf(float v, int j) {
  return __uint_as_float((unsigned)__builtin_amdgcn_readlane((int)__float_as_uint(v), j));
}
__device__ __forceinline__ __half2 xorh(__half2 v, int m) {
  int i = *(int*)&v;
  i = __shfl_xor(i, m);
  return *(__half2*)&i;
}

// ---------------- K1: edge binning (blocks < nch) || W-prep (last 8) --------
__global__ __launch_bounds__(256) void k_build1(
    const int* __restrict__ srcA, const int* __restrict__ dstA,
    int* __restrict__ pcur, unsigned* __restrict__ parts,
    int* __restrict__ ovf, int* __restrict__ ovf_cnt,
    const float* __restrict__ W1, const float* __restrict__ W2,
    _Float16* __restrict__ Wf1, _Float16* __restrict__ Wf2,
    int E, int N, int DPP, int nch, int ovfcap) {
  if ((int)blockIdx.x >= nch) {
    int t = ((int)blockIdx.x - nch) * 256 + (int)threadIdx.x;
    const int stride = 8 * 256;
    for (int i = t; i < 8 * 4 * 64 * 8; i += stride) {
      int j = i & 7, l = (i >> 3) & 63, kk = (i >> 9) & 3, cb = i >> 11;
      int k = kk * 32 + (l >> 4) * 8 + j, c = cb * 16 + (l & 15);
      Wf1[i] = (_Float16)W1[k * 128 + c];
    }
    for (int i = t; i < 4 * 4 * 64 * 8; i += stride) {
      int j = i & 7, l = (i >> 3) & 63, kk = (i >> 9) & 3, cb = i >> 11;
      int k = kk * 32 + (l >> 4) * 8 + j, c = cb * 16 + (l & 15);
      Wf2[i] = (_Float16)W2[k * 64 + c];
    }
    return;
  }
  __shared__ int hist[NPARTS];
  __shared__ int base[NPARTS];
  const int tot = E + N;
  const int c = blockIdx.x;
  hist[threadIdx.x] = 0;
  __syncthreads();
  const int beg = c * CHUNK;
  int pp[16], rr[16];
  unsigned pk[16];
  int dd[16], ss[16];
#pragma unroll
  for (int j = 0; j < 16; ++j) {
    int e = beg + j * 256 + (int)threadIdx.x;
    int d = -1, s = 0;
    if (e < tot) {
      if (e < E) { d = dstA[e]; s = srcA[e]; } else { d = s = e - E; }
    }
    int p = (d >= 0) ? (d / DPP) : -1;
    pp[j] = p;
    dd[j] = d; ss[j] = s;
    pk[j] = (p >= 0) ? (((unsigned)(d - p * DPP) << SRCB) | (unsigned)s) : 0u;
    rr[j] = (p >= 0) ? atomicAdd(&hist[p], 1) : 0;
  }
  __syncthreads();
  base[threadIdx.x] = atomicAdd(&pcur[threadIdx.x], hist[threadIdx.x]);
  __syncthreads();
#pragma unroll
  for (int j = 0; j < 16; ++j) {
    int p = pp[j];
    if (p < 0) continue;
    int pos = base[p] + rr[j];
    if (pos < PCAP) {
      parts[(size_t)p * PCAP + pos] = pk[j];
    } else {
      int o = atomicAdd(ovf_cnt, 1);
      if (o < ovfcap) { ovf[2 * o] = dd[j]; ovf[2 * o + 1] = ss[j]; }
    }
  }
}

// ---------------- MFMA GEMM body (16 rows/wave, K=128) ----------------------
template <int C, typename XT>
__device__ __forceinline__ void gemm_mfma_body(
    const XT* __restrict__ X, const _Float16* __restrict__ Wf,
    const float* __restrict__ atts, const float* __restrict__ attd,
    __half* __restrict__ XLh, float* __restrict__ a_s, float* __restrict__ a_d,
    int N, int bid) {
  constexpr int NCB = C / 16;
  const int lane = threadIdx.x & 63;
  const int wv = threadIdx.x >> 6;
  const int r0 = bid * 64 + wv * 16;
  const int arow = lane & 15;
  const int grp = lane >> 4;
  const int r = r0 + arow;
  const int rsafe = (r < N) ? r : (N - 1);

  float av[NCB], dv[NCB];
#pragma unroll
  for (int cb = 0; cb < NCB; ++cb) {
    av[cb] = atts[cb * 16 + arow];
    dv[cb] = attd[cb * 16 + arow];
  }

  f16x8 af[4];
  if constexpr (sizeof(XT) == 4) {
    const float* xr = (const float*)X + (size_t)rsafe * 128 + grp * 8;
#pragma unroll
    for (int kk = 0; kk < 4; ++kk) {
      float4 u0 = *(const float4*)(xr + kk * 32);
      float4 u1 = *(const float4*)(xr + kk * 32 + 4);
      af[kk][0] = (_Float16)u0.x; af[kk][1] = (_Float16)u0.y;
      af[kk][2] = (_Float16)u0.z; af[kk][3] = (_Float16)u0.w;
      af[kk][4] = (_Float16)u1.x; af[kk][5] = (_Float16)u1.y;
      af[kk][6] = (_Float16)u1.z; af[kk][7] = (_Float16)u1.w;
    }
  } else {
    const __half* xr = (const __half*)X + (size_t)rsafe * 128 + grp * 8;
#pragma unroll
    for (int kk = 0; kk < 4; ++kk)
      af[kk] = *(const f16x8*)(xr + kk * 32);
  }

  float ps[4] = {0.f, 0.f, 0.f, 0.f};
  float pd[4] = {0.f, 0.f, 0.f, 0.f};

#pragma unroll
  for (int cb = 0; cb < NCB; ++cb) {
    f32x4 acc = {0.f, 0.f, 0.f, 0.f};
#pragma unroll
    for (int kk = 0; kk < 4; ++kk) {
      f16x8 bf = *(const f16x8*)(Wf + ((size_t)(cb * 4 + kk) * 64 + lane) * 8);
      acc = __builtin_amdgcn_mfma_f32_16x16x32_f16(af[kk], bf, acc, 0, 0, 0);
    }
    const int ocol = cb * 16 + arow;
#pragma unroll
    for (int i = 0; i < 4; ++i) {
      const int orow = r0 + grp * 4 + i;
      if (orow < N) XLh[(size_t)orow * C + ocol] = (__half)(_Float16)acc[i];
      ps[i] = fmaf(acc[i], av[cb], ps[i]);
      pd[i] = fmaf(acc[i], dv[cb], pd[i]);
    }
  }
#pragma unroll
  for (int m = 1; m < 16; m <<= 1) {
#pragma unroll
    for (int i = 0; i < 4; ++i) {
      ps[i] += __shfl_xor(ps[i], m);
      pd[i] += __shfl_xor(pd[i], m);
    }
  }
  if (arow == 0) {
#pragma unroll
    for (int i = 0; i < 4; ++i) {
      const int orow = r0 + grp * 4 + i;
      if (orow < N) { a_s[orow] = ps[i]; a_d[orow] = pd[i]; }
    }
  }
}

// ---------------- K2: gemm_l1 (blocks < gb) || CSR place+scan (last 256) ----
struct PlaceSmem {
  int sc[NPARTS];
  int l_cnt[DPPMAX];
  int l_off[DPPMAX];
  int l_out[PCAP];
};

__global__ __launch_bounds__(256) void k_gemm1_place(
    const float* __restrict__ X, const _Float16* __restrict__ Wf,
    const float* __restrict__ atts, const float* __restrict__ attd,
    __half* __restrict__ XLh, float* __restrict__ a_s, float* __restrict__ a_d,
    int N, const unsigned* __restrict__ parts, const int* __restrict__ pcur,
    int* __restrict__ rowptr, int* __restrict__ seidx,
    int DPP, int nparts, int gb) {
  __shared__ PlaceSmem sm;
  if ((int)blockIdx.x < gb) {
    gemm_mfma_body<128, float>(X, Wf, atts, attd, XLh, a_s, a_d, N, blockIdx.x);
    return;
  }
  const int p = (int)blockIdx.x - gb;
  const int t = threadIdx.x;
  sm.sc[t] = min(pcur[t], PCAP);
  __syncthreads();
  for (int o = 1; o < NPARTS; o <<= 1) {
    int x = (t >= o) ? sm.sc[t - o] : 0;
    __syncthreads();
    sm.sc[t] += x;
    __syncthreads();
  }
  const int base = (p == 0) ? 0 : sm.sc[p - 1];
  const int n = sm.sc[p] - base;
  const int d0 = p * DPP;
  const int ndst = min(DPP, N - d0);
  const unsigned* pe = parts + (size_t)p * PCAP;

  for (int i = t; i < ndst; i += 256) sm.l_cnt[i] = 0;
  __syncthreads();
  for (int i = t; i < n; i += 256) {
    unsigned e = pe[i];
    atomicAdd(&sm.l_cnt[e >> SRCB], 1);
  }
  __syncthreads();
  if (t == 0) {
    int run = 0;
    for (int i = 0; i < ndst; ++i) { sm.l_off[i] = run; run += sm.l_cnt[i]; }
  }
  __syncthreads();
  for (int i = t; i < ndst; i += 256) {
    rowptr[d0 + i] = base + sm.l_off[i];
    sm.l_cnt[i] = sm.l_off[i];
  }
  if (p == nparts - 1 && t == 0) rowptr[N] = sm.sc[nparts - 1];
  __syncthreads();
  for (int i = t; i < n; i += 256) {
    unsigned e = pe[i];
    int pos = atomicAdd(&sm.l_cnt[e >> SRCB], 1);
    sm.l_out[pos] = (int)(e & ((1u << SRCB) - 1u));
  }
  __syncthreads();
  for (int i = t; i < n; i += 256)
    seidx[base + i] = sm.l_out[i];
}

__global__ __launch_bounds__(256) void k_gemm_l2(
    const __half* __restrict__ X, const _Float16* __restrict__ Wf,
    const float* __restrict__ atts, const float* __restrict__ attd,
    __half* __restrict__ XLh, float* __restrict__ a_s, float* __restrict__ a_d,
    int N) {
  gemm_mfma_body<64, __half>(X, Wf, atts, attd, XLh, a_s, a_d, N, blockIdx.x);
}

// -------- aggr layer 1 (C=128): quad-edge, 16B/lane, pk_fma, fp16 h out -----
__global__ __launch_bounds__(256) void k_aggr_l1(
    const __half* __restrict__ XLh, const float* __restrict__ as_,
    const float* __restrict__ ad_, const int* __restrict__ rowptr,
    const int* __restrict__ seidx, const int* __restrict__ ovf,
    const int* __restrict__ ovf_cnt, const float* __restrict__ bias,
    __half* __restrict__ OUT, int N) {
  constexpr int C = 128;
  const int lane = threadIdx.x & 63;
  const int wid = threadIdx.x >> 6;
  const int q = lane >> 4;            // quarter-wave: which edge of the quad
  const int li = lane & 15;           // col group: cols 8*li .. 8*li+7
  const int novf = *ovf_cnt;          // 0 in practice
  float bb[8];
#pragma unroll
  for (int j = 0; j < 8; ++j) bb[j] = bias[8 * li + j];

  for (int d = blockIdx.x * 4 + wid; d < N; d += gridDim.x * 4) {
    const int beg = rowptr[d], end = rowptr[d + 1];
    const int nb = end - beg;
    const float adst = ad_[d];

    // softmax denominator (max-free: logits bounded)
    float s;
    int sv = 0; float ev = 0.f;
    if (nb <= 64) {
      if (lane < nb) {
        sv = seidx[beg + lane];
        float t = as_[sv] + adst;
        t = t > 0.f ? t : 0.2f * t;
        ev = __expf(t);
      }
      s = ev;
    } else {
      s = 0.f;
      for (int i = beg + lane; i < end; i += 64) {
        int s2 = seidx[i];
        float t = as_[s2] + adst;
        t = t > 0.f ? t : 0.2f * t;
        s += __expf(t);
      }
    }
#pragma unroll
    for (int o = 32; o; o >>= 1) s += __shfl_xor(s, o);

    if (novf > 0) {
      float so = 0.f;
      for (int i = lane; i < novf; i += 64) {
        if (ovf[2 * i] == d) {
          float t = as_[ovf[2 * i + 1]] + adst;
          t = t > 0.f ? t : 0.2f * t;
          so += __expf(t);
        }
      }
#pragma unroll
      for (int o = 32; o; o >>= 1) so += __shfl_xor(so, o);
      s += so;
    }
    const float inv = 1.f / (s + 1e-16f);

    __half2 ac01 = __floats2half2_rn(0.f, 0.f);
    __half2 ac23 = __floats2half2_rn(0.f, 0.f);
    __half2 ac45 = __floats2half2_rn(0.f, 0.f);
    __half2 ac67 = __floats2half2_rn(0.f, 0.f);
    // quad-edge: 4 uniform readlane pairs, 2-level cndmask select by quarter,
    // 16B/lane load (full 256B row per edge-quarter), packed-fp16 FMA.
    auto quad = [&](int vsrc, float vw, int j, int cnt) {
      const int j0 = 4 * j;
      const int s0 = bcasti(vsrc, j0);
      const float w0 = bcastf(vw, j0);
      int s1 = s0, s2 = s0, s3 = s0;
      float w1 = 0.f, w2 = 0.f, w3 = 0.f;
      if (j0 + 1 < cnt) { s1 = bcasti(vsrc, j0 + 1); w1 = bcastf(vw, j0 + 1); }
      if (j0 + 2 < cnt) { s2 = bcasti(vsrc, j0 + 2); w2 = bcastf(vw, j0 + 2); }
      if (j0 + 3 < cnt) { s3 = bcasti(vsrc, j0 + 3); w3 = bcastf(vw, j0 + 3); }
      const int sA = (q & 1) ? s1 : s0;
      const int sB = (q & 1) ? s3 : s2;
      const int sb = (q & 2) ? sB : sA;
      const float wA = (q & 1) ? w1 : w0;
      const float wB = (q & 1) ? w3 : w2;
      const float wj = (q & 2) ? wB : wA;
      const unsigned off = ((unsigned)sb << 8) + ((unsigned)li << 4);
      const uint4 raw = *(const uint4*)((const char*)XLh + off);
      const __half2 wh = __float2half2_rn(wj);
      ac01 = __hfma2(wh, *(const __half2*)&raw.x, ac01);
      ac23 = __hfma2(wh, *(const __half2*)&raw.y, ac23);
      ac45 = __hfma2(wh, *(const __half2*)&raw.z, ac45);
      ac67 = __hfma2(wh, *(const __half2*)&raw.w, ac67);
    };

    if (nb <= 64) {
      const float wv = ev * inv;
      const int np = (nb + 3) >> 2;
      int j = 0;
      for (; j + 4 <= np; j += 4) {
        quad(sv, wv, j, nb); quad(sv, wv, j + 1, nb);
        quad(sv, wv, j + 2, nb); quad(sv, wv, j + 3, nb);
      }
      for (; j < np; ++j) quad(sv, wv, j, nb);
    } else {
      for (int i0 = beg; i0 < end; i0 += 64) {
        const int nc = min(64, end - i0);
        int sc = 0; float wc = 0.f;
        if (lane < nc) {
          sc = seidx[i0 + lane];
          float t = as_[sc] + adst;
          t = t > 0.f ? t : 0.2f * t;
          wc = __expf(t) * inv;
        }
        const int np = (nc + 3) >> 2;
        for (int j = 0; j < np; ++j) quad(sc, wc, j, nc);
      }
    }

    // merge the four quarter-wave edge partials (packed)
    ac01 = __hadd2(ac01, xorh(ac01, 16));
    ac01 = __hadd2(ac01, xorh(ac01, 32));
    ac23 = __hadd2(ac23, xorh(ac23, 16));
    ac23 = __hadd2(ac23, xorh(ac23, 32));
    ac45 = __hadd2(ac45, xorh(ac45, 16));
    ac45 = __hadd2(ac45, xorh(ac45, 32));
    ac67 = __hadd2(ac67, xorh(ac67, 16));
    ac67 = __hadd2(ac67, xorh(ac67, 32));
    float2 f01 = __half22float2(ac01);
    float2 f23 = __half22float2(ac23);
    float2 f45 = __half22float2(ac45);
    float2 f67 = __half22float2(ac67);
    float a[8] = {f01.x, f01.y, f23.x, f23.y, f45.x, f45.y, f67.x, f67.y};

    if (novf > 0) {  // cold overflow adds, post-merge, fp32
      for (int i = 0; i < novf; ++i) {
        if (ovf[2 * i] != d) continue;
        int os = ovf[2 * i + 1];
        float t = as_[os] + adst;
        t = t > 0.f ? t : 0.2f * t;
        float wj = __expf(t) * inv;
        const float4 raw = *(const float4*)(XLh + (size_t)os * C + li * 8);
        const __half2* hp = (const __half2*)&raw;
#pragma unroll
        for (int k = 0; k < 4; ++k) {
          float2 xv = __half22float2(hp[k]);
          a[2 * k] = fmaf(wj, xv.x, a[2 * k]);
          a[2 * k + 1] = fmaf(wj, xv.y, a[2 * k + 1]);
        }
      }
    }

    if (q == 0) {
      __half2 pk[4];
#pragma unroll
      for (int k = 0; k < 4; ++k) {
        float o0 = a[2 * k] + bb[2 * k];
        float o1 = a[2 * k + 1] + bb[2 * k + 1];
        o0 = o0 > 0.f ? o0 : 0.01f * o0;   // inter-layer leaky relu
        o1 = o1 > 0.f ? o1 : 0.01f * o1;
        pk[k] = __floats2half2_rn(o0, o1);
      }
      *(uint4*)(OUT + (size_t)d * C + li * 8) = *(uint4*)pk;
    }
  }
}

// ---- aggr layer 2 (C=64): quad-edge pk_fma gather + fused column sums ------
// OUT receives exp(o) directly (k_norm divides only).
__global__ __launch_bounds__(256) void k_aggr2(
    const __half* __restrict__ XLh, const float* __restrict__ as_,
    const float* __restrict__ ad_, const int* __restrict__ rowptr,
    const int* __restrict__ seidx, const int* __restrict__ ovf,
    const int* __restrict__ ovf_cnt, const float* __restrict__ bias,
    float* __restrict__ OUT, float* __restrict__ csum8, int N) {
  constexpr int C = 64;
  const int lane = threadIdx.x & 63;
  const int wid = threadIdx.x >> 6;
  const int q = lane >> 4;            // quarter-wave: which edge of the quad
  const int li = lane & 15;           // cols 4*li .. 4*li+3
  const int novf = *ovf_cnt;
  float bb[4];
#pragma unroll
  for (int j = 0; j < 4; ++j) bb[j] = bias[4 * li + j];
  float cs0 = 0.f, cs1 = 0.f, cs2 = 0.f, cs3 = 0.f;

  for (int d = blockIdx.x * 4 + wid; d < N; d += gridDim.x * 4) {
    const int beg = rowptr[d], end = rowptr[d + 1];
    const int nb = end - beg;
    const float adst = ad_[d];

    float s;
    int sv = 0; float ev = 0.f;
    if (nb <= 64) {
      if (lane < nb) {
        sv = seidx[beg + lane];
        float t = as_[sv] + adst;
        t = t > 0.f ? t : 0.2f * t;
        ev = __expf(t);
      }
      s = ev;
    } else {
      s = 0.f;
      for (int i = beg + lane; i < end; i += 64) {
        int s2 = seidx[i];
        float t = as_[s2] + adst;
        t = t > 0.f ? t : 0.2f * t;
        s += __expf(t);
      }
    }
#pragma unroll
    for (int o = 32; o; o >>= 1) s += __shfl_xor(s, o);

    if (novf > 0) {
      float so = 0.f;
      for (int i = lane; i < novf; i += 64) {
        if (ovf[2 * i] == d) {
          float t = as_[ovf[2 * i + 1]] + adst;
          t = t > 0.f ? t : 0.2f * t;
          so += __expf(t);
        }
      }
#pragma unroll
      for (int o = 32; o; o >>= 1) so += __shfl_xor(so, o);
      s += so;
    }
    const float inv = 1.f / (s + 1e-16f);

    __half2 ac01 = __floats2half2_rn(0.f, 0.f);
    __half2 ac23 = __floats2half2_rn(0.f, 0.f);
    auto quad = [&](int vsrc, float vw, int j, int cnt) {
      const int j0 = 4 * j;
      const int s0 = bcasti(vsrc, j0);
      const float w0 = bcastf(vw, j0);
      int s1 = s0, s2 = s0, s3 = s0;
      float w1 = 0.f, w2 = 0.f, w3 = 0.f;
      if (j0 + 1 < cnt) { s1 = bcasti(vsrc, j0 + 1); w1 = bcastf(vw, j0 + 1); }
      if (j0 + 2 < cnt) { s2 = bcasti(vsrc, j0 + 2); w2 = bcastf(vw, j0 + 2); }
      if (j0 + 3 < cnt) { s3 = bcasti(vsrc, j0 + 3); w3 = bcastf(vw, j0 + 3); }
      const int sA = (q & 1) ? s1 : s0;
      const int sB = (q & 1) ? s3 : s2;
      const int sb = (q & 2) ? sB : sA;
      const float wA = (q & 1) ? w1 : w0;
      const float wB = (q & 1) ? w3 : w2;
      const float wj = (q & 2) ? wB : wA;
      const unsigned off = ((unsigned)sb << 7) + ((unsigned)li << 3);
      const uint2 raw = *(const uint2*)((const char*)XLh + off);
      const __half2 wh = __float2half2_rn(wj);
      ac01 = __hfma2(wh, *(const __half2*)&raw.x, ac01);
      ac23 = __hfma2(wh, *(const __half2*)&raw.y, ac23);
    };

    if (nb <= 64) {
      const float wv = ev * inv;
      const int np = (nb + 3) >> 2;
      int j = 0;
      for (; j + 4 <= np; j += 4) {
        quad(sv, wv, j, nb); quad(sv, wv, j + 1, nb);
        quad(sv, wv, j + 2, nb); quad(sv, wv, j + 3, nb);
      }
      for (; j < np; ++j) quad(sv, wv, j, nb);
    } else {
      for (int i0 = beg; i0 < end; i0 += 64) {
        const int nc = min(64, end - i0);
        int sc = 0; float wc = 0.f;
        if (lane < nc) {
          sc = seidx[i0 + lane];
          float t = as_[sc] + adst;
          t = t > 0.f ? t : 0.2f * t;
          wc = __expf(t) * inv;
        }
        const int np = (nc + 3) >> 2;
        for (int j = 0; j < np; ++j) quad(sc, wc, j, nc);
      }
    }

    // merge the four quarter-wave edge partials (packed)
    ac01 = __hadd2(ac01, xorh(ac01, 16));
    ac01 = __hadd2(ac01, xorh(ac01, 32));
    ac23 = __hadd2(ac23, xorh(ac23, 16));
    ac23 = __hadd2(ac23, xorh(ac23, 32));
    float2 f01 = __half22float2(ac01);
    float2 f23 = __half22float2(ac23);
    float a0 = f01.x, a1 = f01.y, a2 = f23.x, a3 = f23.y;

    if (novf > 0) {
      for (int i = 0; i < novf; ++i) {
        if (ovf[2 * i] != d) continue;
        int os = ovf[2 * i + 1];
        float t = as_[os] + adst;
        t = t > 0.f ? t : 0.2f * t;
        float wj = __expf(t) * inv;
        const float2 raw = *(const float2*)(XLh + (size_t)os * C + li * 4);
        float2 x0 = __half22float2(*(const __half2*)&raw.x);
        float2 x1 = __half22float2(*(const __half2*)&raw.y);
        a0 = fmaf(wj, x0.x, a0);
        a1 = fmaf(wj, x0.y, a1);
        a2 = fmaf(wj, x1.x, a2);
        a3 = fmaf(wj, x1.y, a3);
      }
    }

    if (q == 0) {
      float e0 = __expf(a0 + bb[0]);
      float e1 = __expf(a1 + bb[1]);
      float e2 = __expf(a2 + bb[2]);
      float e3 = __expf(a3 + bb[3]);
      *(float4*)&OUT[(size_t)d * C + 4 * li] = make_float4(e0, e1, e2, e3);
      cs0 += e0;
      cs1 += e1;
      cs2 += e2;
      cs3 += e3;
    }
  }

  // block-level reduce of fused column sums -> one atomic per col per block
  __shared__ float csA[4][64];
  if (q == 0) {
    csA[wid][4 * li + 0] = cs0;
    csA[wid][4 * li + 1] = cs1;
    csA[wid][4 * li + 2] = cs2;
    csA[wid][4 * li + 3] = cs3;
  }
  __syncthreads();
  if (threadIdx.x < 64) {
    float tot = csA[0][threadIdx.x] + csA[1][threadIdx.x] +
                csA[2][threadIdx.x] + csA[3][threadIdx.x];
    if (tot != 0.f)
      atomicAdd(&csum8[((int)blockIdx.x & 7) * 64 + (int)threadIdx.x], tot);
  }
}

// ------- normalize: OUT already holds exp(o); divide by column sums ---------
__global__ void k_norm(float* __restrict__ O, const float* __restrict__ csum8,
                       size_t tot4) {
  __shared__ float cs[64];
  if (threadIdx.x < 64) {
    float s = 0.f;
#pragma unroll
    for (int r = 0; r < 8; ++r) s += csum8[r * 64 + (int)threadIdx.x];
    cs[threadIdx.x] = 1.f / s;
  }
  __syncthreads();
  for (size_t i = blockIdx.x * (size_t)blockDim.x + threadIdx.x; i < tot4;
       i += (size_t)gridDim.x * blockDim.x) {
    float4 v = ((float4*)O)[i];
    int c0 = (int)((i * 4) & 63);
    v.x *= cs[c0];
    v.y *= cs[c0 + 1];
    v.z *= cs[c0 + 2];
    v.w *= cs[c0 + 3];
    ((float4*)O)[i] = v;
  }
}

// ---------------------------------------------------------------------------
extern "C" void kernel_launch(void* const* d_in, const int* in_sizes, int n_in,
                              void* d_out, int out_size, void* d_ws, size_t ws_size,
                              hipStream_t stream) {
  const float* x   = (const float*)d_in[0];
  const int*   ei  = (const int*)d_in[1];
  const float* W1  = (const float*)d_in[2];
  const float* as1 = (const float*)d_in[3];
  const float* ad1 = (const float*)d_in[4];
  const float* b1  = (const float*)d_in[5];
  const float* W2  = (const float*)d_in[6];
  const float* as2 = (const float*)d_in[7];
  const float* ad2 = (const float*)d_in[8];
  const float* b2  = (const float*)d_in[9];
  float* out = (float*)d_out;

  const int N = in_sizes[0] / 128;
  const int E = in_sizes[1] / 2;
  const int Etot = E + N;
  const int* srcA = ei;
  const int* dstA = ei + E;
  const int DPP = (N + NPARTS - 1) / NPARTS;          // 391
  const int nparts = (N + DPP - 1) / DPP;             // 256

  char* w = (char*)d_ws;
  auto take = [&](size_t bytes) -> void* {
    void* p = (void*)w;
    w += (bytes + 255) & ~(size_t)255;
    return p;
  };
  __half*    xlh   = (__half*)take((size_t)N * 128 * 2);  // layer-1 XL (fp16)
  __half*    xl2h  = (__half*)take((size_t)N * 64 * 2);   // layer-2 XL (fp16)
  __half*    h     = (__half*)take((size_t)N * 128 * 2);  // layer-1 out (fp16)
  float*     a_s   = (float*)take((size_t)N * 4);
  float*     a_d   = (float*)take((size_t)N * 4);
  int*       zeroB = (int*)take((size_t)(1 + NPARTS + 512) * 4); // ovf_cnt|pcur|csum8
  int*       ovf_cnt = zeroB;
  int*       pcur    = zeroB + 1;
  float*     csum8   = (float*)(zeroB + 1 + NPARTS);
  int*       rowptr = (int*)take((size_t)(N + 1) * 4);
  int*       seidx  = (int*)take((size_t)Etot * 4);
  int*       ovf    = (int*)take((size_t)Etot * 2 * 4);
  unsigned*  parts  = (unsigned*)take((size_t)NPARTS * PCAP * 4);
  _Float16*  wf1    = (_Float16*)take((size_t)8 * 4 * 64 * 8 * 2);
  _Float16*  wf2    = (_Float16*)take((size_t)4 * 4 * 64 * 8 * 2);

  hipMemsetAsync(zeroB, 0, (size_t)(1 + NPARTS + 512) * 4, stream);

  const int nch = (Etot + CHUNK - 1) / CHUNK;
  const int gb = (N + 63) / 64;

  k_build1<<<nch + 8, 256, 0, stream>>>(srcA, dstA, pcur, parts, ovf, ovf_cnt,
                                        W1, W2, wf1, wf2, E, N, DPP, nch, Etot);
  k_gemm1_place<<<gb + NPARTS, 256, 0, stream>>>(
      x, wf1, as1, ad1, xlh, a_s, a_d, N, parts, pcur, rowptr, seidx,
      DPP, nparts, gb);
  k_aggr_l1<<<8192, 256, 0, stream>>>(xlh, a_s, a_d, rowptr, seidx, ovf, ovf_cnt,
                                      b1, h, N);
  k_gemm_l2<<<gb, 256, 0, stream>>>(h, wf2, as2, ad2, xl2h, a_s, a_d, N);
  k_aggr2<<<8192, 256, 0, stream>>>(xl2h, a_s, a_d, rowptr, seidx, ovf, ovf_cnt,
                                    b2, out, csum8, N);
  const size_t tot4 = (size_t)N * 64 / 4;
  k_norm<<<2048, 256, 0, stream>>>(out, csum8, tot4);
}

// Round 16
// 218.327 us; speedup vs baseline: 1.0047x; 1.0047x over previous
//
#include <hip/hip_runtime.h>
#include <hip/hip_fp16.h>
#include <math.h>

// ---------------------------------------------------------------------------
// GAT 2-layer network. MFMA fp16 GEMMs (fp32 accum); fp16 gathered features;
// max-free edge softmax; CSR via binned counting-sort (packed uint32 entries).
// aggr_l1: dual-edge gather (8B/lane, measured-optimal); aggr2: quad-edge
// (8B/lane) with fused exp+column sums; norm is divide-only.
// N=100000, E=1600000 (+N self-loops), d_in=h1=128, h2=64.
// ---------------------------------------------------------------------------

constexpr int NPARTS = 256;   // fixed-width dst partitions
constexpr int PCAP = 8192;    // entries per partition (avg 6640, +19 sigma)
constexpr int CHUNK = 4096;   // edges per phase-A block-chunk
constexpr int DPPMAX = 400;   // max dsts per partition (391) -> dloc < 2^15
constexpr int SRCB = 17;      // src id bits (N=100000 < 2^17)

typedef _Float16 f16x8 __attribute__((ext_vector_type(8)));
typedef float f32x4 __attribute__((ext_vector_type(4)));

__device__ __forceinline__ int bcasti(int v, int j) {
  return __builtin_amdgcn_readlane(v, j);
}
__device__ __forceinline__ float bcastf(float v, int j) {
  return __uint_as_float((unsigned)__builtin_amdgcn_readlane((int)__float_as_uint(v), j));
}
__device__ __forceinline__ __half2 xorh(__half2 v, int m) {
  int i = *(int*)&v;
  i = __shfl_xor(i, m);
  return *(__half2*)&i;
}

// ---------------- K1: edge binning (blocks < nch) || W-prep (last 8) --------
__global__ __launch_bounds__(256) void k_build1(
    const int* __restrict__ srcA, const int* __restrict__ dstA,
    int* __restrict__ pcur, unsigned* __restrict__ parts,
    int* __restrict__ ovf, int* __restrict__ ovf_cnt,
    const float* __restrict__ W1, const float* __restrict__ W2,
    _Float16* __restrict__ Wf1, _Float16* __restrict__ Wf2,
    int E, int N, int DPP, int nch, int ovfcap) {
  if ((int)blockIdx.x >= nch) {
    int t = ((int)blockIdx.x - nch) * 256 + (int)threadIdx.x;
    const int stride = 8 * 256;
    for (int i = t; i < 8 * 4 * 64 * 8; i += stride) {
      int j = i & 7, l = (i >> 3) & 63, kk = (i >> 9) & 3, cb = i >> 11;
      int k = kk * 32 + (l >> 4) * 8 + j, c = cb * 16 + (l & 15);
      Wf1[i] = (_Float16)W1[k * 128 + c];
    }
    for (int i = t; i < 4 * 4 * 64 * 8; i += stride) {
      int j = i & 7, l = (i >> 3) & 63, kk = (i >> 9) & 3, cb = i >> 11;
      int k = kk * 32 + (l >> 4) * 8 + j, c = cb * 16 + (l & 15);
      Wf2[i] = (_Float16)W2[k * 64 + c];
    }
    return;
  }
  __shared__ int hist[NPARTS];
  __shared__ int base[NPARTS];
  const int tot = E + N;
  const int c = blockIdx.x;
  hist[threadIdx.x] = 0;
  __syncthreads();
  const int beg = c * CHUNK;
  int pp[16], rr[16];
  unsigned pk[16];
  int dd[16], ss[16];
#pragma unroll
  for (int j = 0; j < 16; ++j) {
    int e = beg + j * 256 + (int)threadIdx.x;
    int d = -1, s = 0;
    if (e < tot) {
      if (e < E) { d = dstA[e]; s = srcA[e]; } else { d = s = e - E; }
    }
    int p = (d >= 0) ? (d / DPP) : -1;
    pp[j] = p;
    dd[j] = d; ss[j] = s;
    pk[j] = (p >= 0) ? (((unsigned)(d - p * DPP) << SRCB) | (unsigned)s) : 0u;
    rr[j] = (p >= 0) ? atomicAdd(&hist[p], 1) : 0;
  }
  __syncthreads();
  base[threadIdx.x] = atomicAdd(&pcur[threadIdx.x], hist[threadIdx.x]);
  __syncthreads();
#pragma unroll
  for (int j = 0; j < 16; ++j) {
    int p = pp[j];
    if (p < 0) continue;
    int pos = base[p] + rr[j];
    if (pos < PCAP) {
      parts[(size_t)p * PCAP + pos] = pk[j];
    } else {
      int o = atomicAdd(ovf_cnt, 1);
      if (o < ovfcap) { ovf[2 * o] = dd[j]; ovf[2 * o + 1] = ss[j]; }
    }
  }
}

// ---------------- MFMA GEMM body (16 rows/wave, K=128) ----------------------
template <int C, typename XT>
__device__ __forceinline__ void gemm_mfma_body(
    const XT* __restrict__ X, const _Float16* __restrict__ Wf,
    const float* __restrict__ atts, const float* __restrict__ attd,
    __half* __restrict__ XLh, float* __restrict__ a_s, float* __restrict__ a_d,
    int N, int bid) {
  constexpr int NCB = C / 16;
  const int lane = threadIdx.x & 63;
  const int wv = threadIdx.x >> 6;
  const int r0 = bid * 64 + wv * 16;
  const int arow = lane & 15;
  const int grp = lane >> 4;
  const int r = r0 + arow;
  const int rsafe = (r < N) ? r : (N - 1);

  float av[NCB], dv[NCB];
#pragma unroll
  for (int cb = 0; cb < NCB; ++cb) {
    av[cb] = atts[cb * 16 + arow];
    dv[cb] = attd[cb * 16 + arow];
  }

  f16x8 af[4];
  if constexpr (sizeof(XT) == 4) {
    const float* xr = (const float*)X + (size_t)rsafe * 128 + grp * 8;
#pragma unroll
    for (int kk = 0; kk < 4; ++kk) {
      float4 u0 = *(const float4*)(xr + kk * 32);
      float4 u1 = *(const float4*)(xr + kk * 32 + 4);
      af[kk][0] = (_Float16)u0.x; af[kk][1] = (_Float16)u0.y;
      af[kk][2] = (_Float16)u0.z; af[kk][3] = (_Float16)u0.w;
      af[kk][4] = (_Float16)u1.x; af[kk][5] = (_Float16)u1.y;
      af[kk][6] = (_Float16)u1.z; af[kk][7] = (_Float16)u1.w;
    }
  } else {
    const __half* xr = (const __half*)X + (size_t)rsafe * 128 + grp * 8;
#pragma unroll
    for (int kk = 0; kk < 4; ++kk)
      af[kk] = *(const f16x8*)(xr + kk * 32);
  }

  float ps[4] = {0.f, 0.f, 0.f, 0.f};
  float pd[4] = {0.f, 0.f, 0.f, 0.f};

#pragma unroll
  for (int cb = 0; cb < NCB; ++cb) {
    f32x4 acc = {0.f, 0.f, 0.f, 0.f};
#pragma unroll
    for (int kk = 0; kk < 4; ++kk) {
      f16x8 bf = *(const f16x8*)(Wf + ((size_t)(cb * 4 + kk) * 64 + lane) * 8);
      acc = __builtin_amdgcn_mfma_f32_16x16x32_f16(af[kk], bf, acc, 0, 0, 0);
    }
    const int ocol = cb * 16 + arow;
#pragma unroll
    for (int i = 0; i < 4; ++i) {
      const int orow = r0 + grp * 4 + i;
      if (orow < N) XLh[(size_t)orow * C + ocol] = (__half)(_Float16)acc[i];
      ps[i] = fmaf(acc[i], av[cb], ps[i]);
      pd[i] = fmaf(acc[i], dv[cb], pd[i]);
    }
  }
#pragma unroll
  for (int m = 1; m < 16; m <<= 1) {
#pragma unroll
    for (int i = 0; i < 4; ++i) {
      ps[i] += __shfl_xor(ps[i], m);
      pd[i] += __shfl_xor(pd[i], m);
    }
  }
  if (arow == 0) {
#pragma unroll
    for (int i = 0; i < 4; ++i) {
      const int orow = r0 + grp * 4 + i;
      if (orow < N) { a_s[orow] = ps[i]; a_d[orow] = pd[i]; }
    }
  }
}

// ---------------- K2: gemm_l1 (blocks < gb) || CSR place+scan (last 256) ----
struct PlaceSmem {
  int sc[NPARTS];
  int l_cnt[DPPMAX];
  int l_off[DPPMAX];
  int l_out[PCAP];
};

__global__ __launch_bounds__(256) void k_gemm1_place(
    const float* __restrict__ X, const _Float16* __restrict__ Wf,
    const float* __restrict__ atts, const float* __restrict__ attd,
    __half* __restrict__ XLh, float* __restrict__ a_s, float* __restrict__ a_d,
    int N, const unsigned* __restrict__ parts, const int* __restrict__ pcur,
    int* __restrict__ rowptr, int* __restrict__ seidx,
    int DPP, int nparts, int gb) {
  __shared__ PlaceSmem sm;
  if ((int)blockIdx.x < gb) {
    gemm_mfma_body<128, float>(X, Wf, atts, attd, XLh, a_s, a_d, N, blockIdx.x);
    return;
  }
  const int p = (int)blockIdx.x - gb;
  const int t = threadIdx.x;
  sm.sc[t] = min(pcur[t], PCAP);
  __syncthreads();
  for (int o = 1; o < NPARTS; o <<= 1) {
    int x = (t >= o) ? sm.sc[t - o] : 0;
    __syncthreads();
    sm.sc[t] += x;
    __syncthreads();
  }
  const int base = (p == 0) ? 0 : sm.sc[p - 1];
  const int n = sm.sc[p] - base;
  const int d0 = p * DPP;
  const int ndst = min(DPP, N - d0);
  const unsigned* pe = parts + (size_t)p * PCAP;

  for (int i = t; i < ndst; i += 256) sm.l_cnt[i] = 0;
  __syncthreads();
  for (int i = t; i < n; i += 256) {
    unsigned e = pe[i];
    atomicAdd(&sm.l_cnt[e >> SRCB], 1);
  }
  __syncthreads();
  if (t == 0) {
    int run = 0;
    for (int i = 0; i < ndst; ++i) { sm.l_off[i] = run; run += sm.l_cnt[i]; }
  }
  __syncthreads();
  for (int i = t; i < ndst; i += 256) {
    rowptr[d0 + i] = base + sm.l_off[i];
    sm.l_cnt[i] = sm.l_off[i];
  }
  if (p == nparts - 1 && t == 0) rowptr[N] = sm.sc[nparts - 1];
  __syncthreads();
  for (int i = t; i < n; i += 256) {
    unsigned e = pe[i];
    int pos = atomicAdd(&sm.l_cnt[e >> SRCB], 1);
    sm.l_out[pos] = (int)(e & ((1u << SRCB) - 1u));
  }
  __syncthreads();
  for (int i = t; i < n; i += 256)
    seidx[base + i] = sm.l_out[i];
}

__global__ __launch_bounds__(256) void k_gemm_l2(
    const __half* __restrict__ X, const _Float16* __restrict__ Wf,
    const float* __restrict__ atts, const float* __restrict__ attd,
    __half* __restrict__ XLh, float* __restrict__ a_s, float* __restrict__ a_d,
    int N) {
  gemm_mfma_body<64, __half>(X, Wf, atts, attd, XLh, a_s, a_d, N, blockIdx.x);
}

// -------- aggr layer 1 (C=128): dual-edge, pk_fma_f16 accum, fp16 h out -----
// (measured-optimal form: 8B/lane, 4 readlanes + 2 cndmask per pair)
__global__ __launch_bounds__(256) void k_aggr_l1(
    const __half* __restrict__ XLh, const float* __restrict__ as_,
    const float* __restrict__ ad_, const int* __restrict__ rowptr,
    const int* __restrict__ seidx, const int* __restrict__ ovf,
    const int* __restrict__ ovf_cnt, const float* __restrict__ bias,
    __half* __restrict__ OUT, int N) {
  constexpr int C = 128;
  const int lane = threadIdx.x & 63;
  const int wid = threadIdx.x >> 6;
  const int grp = lane >> 5;          // which edge of the broadcast pair
  const int l5 = lane & 31;           // col group: cols 4*l5 .. 4*l5+3
  const int novf = *ovf_cnt;          // 0 in practice
  float bb[4];
#pragma unroll
  for (int j = 0; j < 4; ++j) bb[j] = bias[4 * l5 + j];

  for (int d = blockIdx.x * 4 + wid; d < N; d += gridDim.x * 4) {
    const int beg = rowptr[d], end = rowptr[d + 1];
    const int nb = end - beg;
    const float adst = ad_[d];

    // softmax denominator (max-free: logits bounded)
    float s;
    int sv = 0; float ev = 0.f;
    if (nb <= 64) {
      if (lane < nb) {
        sv = seidx[beg + lane];
        float t = as_[sv] + adst;
        t = t > 0.f ? t : 0.2f * t;
        ev = __expf(t);
      }
      s = ev;
    } else {
      s = 0.f;
      for (int i = beg + lane; i < end; i += 64) {
        int s2 = seidx[i];
        float t = as_[s2] + adst;
        t = t > 0.f ? t : 0.2f * t;
        s += __expf(t);
      }
    }
#pragma unroll
    for (int o = 32; o; o >>= 1) s += __shfl_xor(s, o);

    if (novf > 0) {
      float so = 0.f;
      for (int i = lane; i < novf; i += 64) {
        if (ovf[2 * i] == d) {
          float t = as_[ovf[2 * i + 1]] + adst;
          t = t > 0.f ? t : 0.2f * t;
          so += __expf(t);
        }
      }
#pragma unroll
      for (int o = 32; o; o >>= 1) so += __shfl_xor(so, o);
      s += so;
    }
    const float inv = 1.f / (s + 1e-16f);

    __half2 ac01 = __floats2half2_rn(0.f, 0.f);
    __half2 ac23 = __floats2half2_rn(0.f, 0.f);
    auto pair = [&](int vsrc, float vw, int j, int cnt) {
      const int j0 = 2 * j, j1 = 2 * j + 1;
      const int s0 = bcasti(vsrc, j0);
      const float w0 = bcastf(vw, j0);
      int s1 = s0; float w1 = 0.f;
      if (j1 < cnt) { s1 = bcasti(vsrc, j1); w1 = bcastf(vw, j1); }
      const int sb = grp ? s1 : s0;
      const float wj = grp ? w1 : w0;
      const unsigned off = ((unsigned)sb << 8) + ((unsigned)l5 << 3);
      const uint2 raw = *(const uint2*)((const char*)XLh + off);
      const __half2 wh = __float2half2_rn(wj);
      ac01 = __hfma2(wh, *(const __half2*)&raw.x, ac01);
      ac23 = __hfma2(wh, *(const __half2*)&raw.y, ac23);
    };

    if (nb <= 64) {
      const float wv = ev * inv;
      const int np = (nb + 1) >> 1;
      int j = 0;
      for (; j + 4 <= np; j += 4) {
        pair(sv, wv, j, nb); pair(sv, wv, j + 1, nb);
        pair(sv, wv, j + 2, nb); pair(sv, wv, j + 3, nb);
      }
      for (; j < np; ++j) pair(sv, wv, j, nb);
    } else {
      for (int i0 = beg; i0 < end; i0 += 64) {
        const int nc = min(64, end - i0);
        int sc = 0; float wc = 0.f;
        if (lane < nc) {
          sc = seidx[i0 + lane];
          float t = as_[sc] + adst;
          t = t > 0.f ? t : 0.2f * t;
          wc = __expf(t) * inv;
        }
        const int np = (nc + 1) >> 1;
        for (int j = 0; j < np; ++j) pair(sc, wc, j, nc);
      }
    }

    // merge the two half-wave edge partials (packed)
    ac01 = __hadd2(ac01, xorh(ac01, 32));
    ac23 = __hadd2(ac23, xorh(ac23, 32));
    float2 f01 = __half22float2(ac01);
    float2 f23 = __half22float2(ac23);
    float a0 = f01.x, a1 = f01.y, a2 = f23.x, a3 = f23.y;

    if (novf > 0) {  // cold overflow adds, post-merge, fp32
      for (int i = 0; i < novf; ++i) {
        if (ovf[2 * i] != d) continue;
        int os = ovf[2 * i + 1];
        float t = as_[os] + adst;
        t = t > 0.f ? t : 0.2f * t;
        float wj = __expf(t) * inv;
        const float2 raw = *(const float2*)(XLh + (size_t)os * C + l5 * 4);
        float2 x0 = __half22float2(*(const __half2*)&raw.x);
        float2 x1 = __half22float2(*(const __half2*)&raw.y);
        a0 = fmaf(wj, x0.x, a0);
        a1 = fmaf(wj, x0.y, a1);
        a2 = fmaf(wj, x1.x, a2);
        a3 = fmaf(wj, x1.y, a3);
      }
    }

    if (grp == 0) {
      float o0 = a0 + bb[0], o1 = a1 + bb[1];
      float o2 = a2 + bb[2], o3 = a3 + bb[3];
      o0 = o0 > 0.f ? o0 : 0.01f * o0;   // inter-layer leaky relu
      o1 = o1 > 0.f ? o1 : 0.01f * o1;
      o2 = o2 > 0.f ? o2 : 0.01f * o2;
      o3 = o3 > 0.f ? o3 : 0.01f * o3;
      __half2 p0 = __floats2half2_rn(o0, o1);
      __half2 p1 = __floats2half2_rn(o2, o3);
      uint2 u;
      u.x = *(unsigned*)&p0;
      u.y = *(unsigned*)&p1;
      *(uint2*)(OUT + (size_t)d * C + l5 * 4) = u;
    }
  }
}

// ---- aggr layer 2 (C=64): quad-edge pk_fma gather + fused exp/column sums --
// OUT receives exp(o) directly (k_norm divides only).
__global__ __launch_bounds__(256) void k_aggr2(
    const __half* __restrict__ XLh, const float* __restrict__ as_,
    const float* __restrict__ ad_, const int* __restrict__ rowptr,
    const int* __restrict__ seidx, const int* __restrict__ ovf,
    const int* __restrict__ ovf_cnt, const float* __restrict__ bias,
    float* __restrict__ OUT, float* __restrict__ csum8, int N) {
  constexpr int C = 64;
  const int lane = threadIdx.x & 63;
  const int wid = threadIdx.x >> 6;
  const int q = lane >> 4;            // quarter-wave: which edge of the quad
  const int li = lane & 15;           // cols 4*li .. 4*li+3
  const int novf = *ovf_cnt;
  float bb[4];
#pragma unroll
  for (int j = 0; j < 4; ++j) bb[j] = bias[4 * li + j];
  float cs0 = 0.f, cs1 = 0.f, cs2 = 0.f, cs3 = 0.f;

  for (int d = blockIdx.x * 4 + wid; d < N; d += gridDim.x * 4) {
    const int beg = rowptr[d], end = rowptr[d + 1];
    const int nb = end - beg;
    const float adst = ad_[d];

    float s;
    int sv = 0; float ev = 0.f;
    if (nb <= 64) {
      if (lane < nb) {
        sv = seidx[beg + lane];
        float t = as_[sv] + adst;
        t = t > 0.f ? t : 0.2f * t;
        ev = __expf(t);
      }
      s = ev;
    } else {
      s = 0.f;
      for (int i = beg + lane; i < end; i += 64) {
        int s2 = seidx[i];
        float t = as_[s2] + adst;
        t = t > 0.f ? t : 0.2f * t;
        s += __expf(t);
      }
    }
#pragma unroll
    for (int o = 32; o; o >>= 1) s += __shfl_xor(s, o);

    if (novf > 0) {
      float so = 0.f;
      for (int i = lane; i < novf; i += 64) {
        if (ovf[2 * i] == d) {
          float t = as_[ovf[2 * i + 1]] + adst;
          t = t > 0.f ? t : 0.2f * t;
          so += __expf(t);
        }
      }
#pragma unroll
      for (int o = 32; o; o >>= 1) so += __shfl_xor(so, o);
      s += so;
    }
    const float inv = 1.f / (s + 1e-16f);

    __half2 ac01 = __floats2half2_rn(0.f, 0.f);
    __half2 ac23 = __floats2half2_rn(0.f, 0.f);
    auto quad = [&](int vsrc, float vw, int j, int cnt) {
      const int j0 = 4 * j;
      const int s0 = bcasti(vsrc, j0);
      const float w0 = bcastf(vw, j0);
      int s1 = s0, s2 = s0, s3 = s0;
      float w1 = 0.f, w2 = 0.f, w3 = 0.f;
      if (j0 + 1 < cnt) { s1 = bcasti(vsrc, j0 + 1); w1 = bcastf(vw, j0 + 1); }
      if (j0 + 2 < cnt) { s2 = bcasti(vsrc, j0 + 2); w2 = bcastf(vw, j0 + 2); }
      if (j0 + 3 < cnt) { s3 = bcasti(vsrc, j0 + 3); w3 = bcastf(vw, j0 + 3); }
      const int sA = (q & 1) ? s1 : s0;
      const int sB = (q & 1) ? s3 : s2;
      const int sb = (q & 2) ? sB : sA;
      const float wA = (q & 1) ? w1 : w0;
      const float wB = (q & 1) ? w3 : w2;
      const float wj = (q & 2) ? wB : wA;
      const unsigned off = ((unsigned)sb << 7) + ((unsigned)li << 3);
      const uint2 raw = *(const uint2*)((const char*)XLh + off);
      const __half2 wh = __float2half2_rn(wj);
      ac01 = __hfma2(wh, *(const __half2*)&raw.x, ac01);
      ac23 = __hfma2(wh, *(const __half2*)&raw.y, ac23);
    };

    if (nb <= 64) {
      const float wv = ev * inv;
      const int np = (nb + 3) >> 2;
      int j = 0;
      for (; j + 4 <= np; j += 4) {
        quad(sv, wv, j, nb); quad(sv, wv, j + 1, nb);
        quad(sv, wv, j + 2, nb); quad(sv, wv, j + 3, nb);
      }
      for (; j < np; ++j) quad(sv, wv, j, nb);
    } else {
      for (int i0 = beg; i0 < end; i0 += 64) {
        const int nc = min(64, end - i0);
        int sc = 0; float wc = 0.f;
        if (lane < nc) {
          sc = seidx[i0 + lane];
          float t = as_[sc] + adst;
          t = t > 0.f ? t : 0.2f * t;
          wc = __expf(t) * inv;
        }
        const int np = (nc + 3) >> 2;
        for (int j = 0; j < np; ++j) quad(sc, wc, j, nc);
      }
    }

    // merge the four quarter-wave edge partials (packed)
    ac01 = __hadd2(ac01, xorh(ac01, 16));
    ac01 = __hadd2(ac01, xorh(ac01, 32));
    ac23 = __hadd2(ac23, xorh(ac23, 16));
    ac23 = __hadd2(ac23, xorh(ac23, 32));
    float2 f01 = __half22float2(ac01);
    float2 f23 = __half22float2(ac23);
    float a0 = f01.x, a1 = f01.y, a2 = f23.x, a3 = f23.y;

    if (novf > 0) {
      for (int i = 0; i < novf; ++i) {
        if (ovf[2 * i] != d) continue;
        int os = ovf[2 * i + 1];
        float t = as_[os] + adst;
        t = t > 0.f ? t : 0.2f * t;
        float wj = __expf(t) * inv;
        const float2 raw = *(const float2*)(XLh + (size_t)os * C + li * 4);
        float2 x0 = __half22float2(*(const __half2*)&raw.x);
        float2 x1 = __half22float2(*(const __half2*)&raw.y);
        a0 = fmaf(wj, x0.x, a0);
        a1 = fmaf(wj, x0.y, a1);
        a2 = fmaf(wj, x1.x, a2);
        a3 = fmaf(wj, x1.y, a3);
      }
    }

    if (q == 0) {
      float e0 = __expf(a0 + bb[0]);
      float e1 = __expf(a1 + bb[1]);
      float e2 = __expf(a2 + bb[2]);
      float e3 = __expf(a3 + bb[3]);
      *(float4*)&OUT[(size_t)d * C + 4 * li] = make_float4(e0, e1, e2, e3);
      cs0 += e0;
      cs1 += e1;
      cs2 += e2;
      cs3 += e3;
    }
  }

  // block-level reduce of fused column sums -> one atomic per col per block
  __shared__ float csA[4][64];
  if (q == 0) {
    csA[wid][4 * li + 0] = cs0;
    csA[wid][4 * li + 1] = cs1;
    csA[wid][4 * li + 2] = cs2;
    csA[wid][4 * li + 3] = cs3;
  }
  __syncthreads();
  if (threadIdx.x < 64) {
    float tot = csA[0][threadIdx.x] + csA[1][threadIdx.x] +
                csA[2][threadIdx.x] + csA[3][threadIdx.x];
    if (tot != 0.f)
      atomicAdd(&csum8[((int)blockIdx.x & 7) * 64 + (int)threadIdx.x], tot);
  }
}

// ------- normalize: OUT already holds exp(o); divide by column sums ---------
__global__ void k_norm(float* __restrict__ O, const float* __restrict__ csum8,
                       size_t tot4) {
  __shared__ float cs[64];
  if (threadIdx.x < 64) {
    float s = 0.f;
#pragma unroll
    for (int r = 0; r < 8; ++r) s += csum8[r * 64 + (int)threadIdx.x];
    cs[threadIdx.x] = 1.f / s;
  }
  __syncthreads();
  for (size_t i = blockIdx.x * (size_t)blockDim.x + threadIdx.x; i < tot4;
       i += (size_t)gridDim.x * blockDim.x) {
    float4 v = ((float4*)O)[i];
    int c0 = (int)((i * 4) & 63);
    v.x *= cs[c0];
    v.y *= cs[c0 + 1];
    v.z *= cs[c0 + 2];
    v.w *= cs[c0 + 3];
    ((float4*)O)[i] = v;
  }
}

// ---------------------------------------------------------------------------
extern "C" void kernel_launch(void* const* d_in, const int* in_sizes, int n_in,
                              void* d_out, int out_size, void* d_ws, size_t ws_size,
                              hipStream_t stream) {
  const float* x   = (const float*)d_in[0];
  const int*   ei  = (const int*)d_in[1];
  const float* W1  = (const float*)d_in[2];
  const float* as1 = (const float*)d_in[3];
  const float* ad1 = (const float*)d_in[4];
  const float* b1  = (const float*)d_in[5];
  const float* W2  = (const float*)d_in[6];
  const float* as2 = (const float*)d_in[7];
  const float* ad2 = (const float*)d_in[8];
  const float* b2  = (const float*)d_in[9];
  float* out = (float*)d_out;

  const int N = in_sizes[0] / 128;
  const int E = in_sizes[1] / 2;
  const int Etot = E + N;
  const int* srcA = ei;
  const int* dstA = ei + E;
  const int DPP = (N + NPARTS - 1) / NPARTS;          // 391
  const int nparts = (N + DPP - 1) / DPP;             // 256

  char* w = (char*)d_ws;
  auto take = [&](size_t bytes) -> void* {
    void* p = (void*)w;
    w += (bytes + 255) & ~(size_t)255;
    return p;
  };
  __half*    xlh   = (__half*)take((size_t)N * 128 * 2);  // layer-1 XL (fp16)
  __half*    xl2h  = (__half*)take((size_t)N * 64 * 2);   // layer-2 XL (fp16)
  __half*    h     = (__half*)take((size_t)N * 128 * 2);  // layer-1 out (fp16)
  float*     a_s   = (float*)take((size_t)N * 4);
  float*     a_d   = (float*)take((size_t)N * 4);
  int*       zeroB = (int*)take((size_t)(1 + NPARTS + 512) * 4); // ovf_cnt|pcur|csum8
  int*       ovf_cnt = zeroB;
  int*       pcur    = zeroB + 1;
  float*     csum8   = (float*)(zeroB + 1 + NPARTS);
  int*       rowptr = (int*)take((size_t)(N + 1) * 4);
  int*       seidx  = (int*)take((size_t)Etot * 4);
  int*       ovf    = (int*)take((size_t)Etot * 2 * 4);
  unsigned*  parts  = (unsigned*)take((size_t)NPARTS * PCAP * 4);
  _Float16*  wf1    = (_Float16*)take((size_t)8 * 4 * 64 * 8 * 2);
  _Float16*  wf2    = (_Float16*)take((size_t)4 * 4 * 64 * 8 * 2);

  hipMemsetAsync(zeroB, 0, (size_t)(1 + NPARTS + 512) * 4, stream);

  const int nch = (Etot + CHUNK - 1) / CHUNK;
  const int gb = (N + 63) / 64;

  k_build1<<<nch + 8, 256, 0, stream>>>(srcA, dstA, pcur, parts, ovf, ovf_cnt,
                                        W1, W2, wf1, wf2, E, N, DPP, nch, Etot);
  k_gemm1_place<<<gb + NPARTS, 256, 0, stream>>>(
      x, wf1, as1, ad1, xlh, a_s, a_d, N, parts, pcur, rowptr, seidx,
      DPP, nparts, gb);
  k_aggr_l1<<<8192, 256, 0, stream>>>(xlh, a_s, a_d, rowptr, seidx, ovf, ovf_cnt,
                                      b1, h, N);
  k_gemm_l2<<<gb, 256, 0, stream>>>(h, wf2, as2, ad2, xl2h, a_s, a_d, N);
  k_aggr2<<<8192, 256, 0, stream>>>(xl2h, a_s, a_d, rowptr, seidx, ovf, ovf_cnt,
                                    b2, out, csum8, N);
  const size_t tot4 = (size_t)N * 64 / 4;
  k_norm<<<2048, 256, 0, stream>>>(out, csum8, tot4);
}